// Round 6
// baseline (110.299 us; speedup 1.0000x reference)
//
#include <hip/hip_runtime.h>

// DepthDeformConv — round 14: ROLLED tap loop (I$ theory).
//   Main is pinned at ~43-50us across r8-r13 despite swapping data sources
//   (LDS/L2), barriers (9/0), occupancy (2/4 waves per SIMD) and hand
//   pipelining -> busiest pipe only ~19% busy. The invariant: every round
//   was a fully-unrolled ~20KB straight-line body executed once per block,
//   i.e. ~300 I$ lines streamed cold from L2 per wave. Fix: roll the tap
//   loop (body ~2KB, I$-hot after iter 1). Runtime-kt support without
//   scratch: offset/mask rows staged to LDS (13.5KB, broadcast ds_read
//   per tap), kx/ky maintained incrementally, weight addr is arithmetic.
//   Window/swizzle/fallback/epilogue identical to r11 -> absmax unchanged.

typedef __attribute__((ext_vector_type(8))) short bf16x8;
typedef __attribute__((ext_vector_type(4))) float f32x4;
typedef __attribute__((ext_vector_type(4))) unsigned int u32x4;

#define HH 128
#define WW 128
#define CC 64
#define OO 64
#define HW (128 * 128)

__device__ __forceinline__ unsigned f32_to_bf16_rne(float f) {
    unsigned u = __float_as_uint(f);
    return (u + 0x7FFFu + ((u >> 16) & 1u)) >> 16;
}

// ---------------- kernel 1: fused NCHW->NHWC bf16 + weight repack ----------------
__global__ __launch_bounds__(256)
void prep_fused14(const float* __restrict__ input,
                  unsigned short* __restrict__ nhwc,
                  const float* __restrict__ weight,
                  unsigned short* __restrict__ wT2)
{
    __shared__ unsigned tile[64][33];
    const int tid = threadIdx.x;
    const int blk = blockIdx.x;

    if (blk >= 2048) {
        // weight repack: wT2[(kt*8 + c8)*64 + o] = bf16 w for ch c8*8..+7, tap kt
        const int d  = (blk - 2048) * 256 + tid;    // 0..4607
        const int o  = d & 63;
        const int k8 = d >> 6;                      // 0..71
        const int kt = k8 >> 3;
        const int c8 = k8 & 7;
        u32x4 pk;
        #pragma unroll
        for (int jj = 0; jj < 4; ++jj) {
            unsigned lo = f32_to_bf16_rne(weight[o * 576 + (c8 * 8 + 2 * jj)     * 9 + kt]);
            unsigned hi = f32_to_bf16_rne(weight[o * 576 + (c8 * 8 + 2 * jj + 1) * 9 + kt]);
            pk[jj] = lo | (hi << 16);
        }
        *(u32x4*)(wT2 + (size_t)d * 8) = pk;
        return;
    }

    const int b  = blk >> 9;
    const int y  = (blk >> 2) & 127;
    const int xbase = (blk & 3) * 32;
    #pragma unroll
    for (int it = 0; it < 8; ++it) {
        int flat = it * 256 + tid;          // 0..2047
        int c = flat >> 5, x = flat & 31;
        float v = input[((b * 64 + c) * 128 + y) * 128 + xbase + x];
        tile[c][x] = f32_to_bf16_rne(v);
    }
    __syncthreads();
    {
        int x = tid >> 3, cg = tid & 7;     // 32x * 8 channel-groups
        unsigned r0 = tile[cg * 8 + 0][x], r1 = tile[cg * 8 + 1][x];
        unsigned r2 = tile[cg * 8 + 2][x], r3 = tile[cg * 8 + 3][x];
        unsigned r4 = tile[cg * 8 + 4][x], r5 = tile[cg * 8 + 5][x];
        unsigned r6 = tile[cg * 8 + 6][x], r7 = tile[cg * 8 + 7][x];
        u32x4 pk;
        pk[0] = r0 | (r1 << 16); pk[1] = r2 | (r3 << 16);
        pk[2] = r4 | (r5 << 16); pk[3] = r6 | (r7 << 16);
        *(u32x4*)(nhwc + ((size_t)((b * 128 + y) * 128 + xbase + x)) * 64 + cg * 8) = pk;
    }
}

// ---------------- kernel 2: fused sample + MFMA, rolled tap loop ----------------
__global__ __launch_bounds__(512, 2)
void ddc_roll14(const unsigned short* __restrict__ nhwc,
                const unsigned short* __restrict__ wT2,
                const float* __restrict__ offset,
                const float* __restrict__ mask,
                const float* __restrict__ bias,
                float* __restrict__ out)
{
    // 8-row bf16 NHWC window, chunk-swizzled: LDS u32x4 index
    //   idx(slot,x,c8pos) = slot*1024 + x*8 + c8pos, holding source chunk
    //   c8pos ^ (x&7). Reader at chunk ch uses pos = ch ^ (x&7).
    __shared__ u32x4 win[8192];            // 128 KB
    __shared__ float sten[3456];           // 13.5 KB: off rows (2304) + mask rows (1152)

    const int blk0 = blockIdx.x;           // 512 = 4b * 128h
    const int blk  = (blk0 & 7) * 64 + (blk0 >> 3);   // XCD-chunked swizzle
    const int b    = blk >> 7;
    const int h    = blk & 127;
    const int tid  = threadIdx.x;
    const int wave = tid >> 6;             // 8 pixel groups
    const int lane = tid & 63;
    const int l15  = lane & 15;            // pixel within group / o-row (A)
    const int kq   = lane >> 4;            // k-chunk quad (0..3)
    const int wpix = wave * 16 + l15;      // w coordinate (full 128 row)

    f32x4 acc[4];
    #pragma unroll
    for (int mt = 0; mt < 4; ++mt) acc[mt] = (f32x4){0.f, 0.f, 0.f, 0.f};

    const unsigned short* nb = nhwc + (size_t)b * HW * CC;
    const u32x4* wsrc = (const u32x4*)wT2;

    // ---- stage offset/mask rows into LDS (coalesced, covered by barrier) ----
    #pragma unroll
    for (int it = 0; it < 7; ++it) {
        const int f = it * 512 + tid;                 // 0..3583
        if (f < 2304) {                               // offset rows j=0..17
            const int j = f >> 7, x = f & 127;
            sten[f] = offset[((b * 18 + j) * 128 + h) * 128 + x];
        } else if (f < 3456) {                        // mask rows j=0..8
            const int g = f - 2304;
            const int j = g >> 7, x = g & 127;
            sten[f] = mask[((b * 9 + j) * 128 + h) * 128 + x];
        }
    }

    // ---- stage window rows h-3..h+4 (swizzled source, linear LDS dest) ----
    #pragma unroll
    for (int i = 0; i < 16; ++i) {
        const int slot = i >> 1;                      // uniform per i
        const int y = h - 3 + slot;
        if (y >= 0 && y < HH) {
            const int q  = ((i & 1) << 9) + tid;      // 0..1023 within row
            const int x  = q >> 3;
            const int c8 = q & 7;
            win[slot * 1024 + q] =
                *(const u32x4*)(nb + ((size_t)(y * WW + x)) * CC + ((c8 ^ (x & 7)) << 3));
        }
    }
    __syncthreads();                                  // the ONLY barrier

    // ---- K loop: ROLLED (body ~2KB, I$-resident) ----
    int ky = 0, kx = 0;
    #pragma unroll 1
    for (int kt = 0; kt < 9; ++kt) {
        // (1) weight loads first: longest latency, address needs only kt
        const u32x4* wp0 = wsrc + (kt * 8 + kq) * 64 + l15;        // ks=0
        const u32x4* wp1 = wsrc + (kt * 8 + 4 + kq) * 64 + l15;    // ks=1
        const u32x4 wa0 = wp0[0],  wa1 = wp0[16], wa2 = wp0[32], wa3 = wp0[48];
        const u32x4 wb0 = wp1[0],  wb1 = wp1[16], wb2 = wp1[32], wb3 = wp1[48];

        // (2) stencil scalars from LDS (broadcast, conflict-free)
        const float oy = sten[((2 * kt)     << 7) + wpix];
        const float ox = sten[((2 * kt + 1) << 7) + wpix];
        const float m  = sten[2304 + (kt << 7) + wpix];

        // (3) stencil math
        const float py = (float)(h - 1 + ky) + oy;
        const float px = (float)(wpix - 1 + kx) + ox;
        const float y0f = floorf(py), x0f = floorf(px);
        const int y0 = (int)y0f, x0 = (int)x0f;
        const float wy = py - y0f, wx = px - x0f;
        const int y1 = y0 + 1, x1 = x0 + 1;
        const bool vy0 = (y0 >= 0) & (y0 < HH);
        const bool vy1 = (y1 >= 0) & (y1 < HH);
        const bool vx0 = (x0 >= 0) & (x0 < WW);
        const bool vx1 = (x1 >= 0) & (x1 < WW);
        const int y0c = min(max(y0, 0), HH - 1), y1c = min(max(y1, 0), HH - 1);
        const int x0c = min(max(x0, 0), WW - 1), x1c = min(max(x1, 0), WW - 1);
        const float wy1 = 1.f - wy, wx1 = 1.f - wx;
        const float c00 = (vy0 && vx0) ? wy1 * wx1 * m : 0.f;
        const float c01 = (vy0 && vx1) ? wy1 * wx  * m : 0.f;
        const float c10 = (vy1 && vx0) ? wy  * wx1 * m : 0.f;
        const float c11 = (vy1 && vx1) ? wy  * wx  * m : 0.f;

        const int s0 = y0c - (h - 3), s1 = y1c - (h - 3);
        const bool in0 = ((unsigned)s0 < 8u);
        const bool in1 = ((unsigned)s1 < 8u);
        const int r0 = (in0 ? s0 : 0) * 1024;
        const int r1 = (in1 ? s1 : 0) * 1024;
        const int bx0 = x0c * 8, sx0 = x0c & 7;
        const int bx1 = x1c * 8, sx1 = x1c & 7;

        // (4) all 8 corner reads issued together (both ks)
        const int ch0 = kq, ch1 = 4 + kq;
        u32x4 a00 = win[r0 + bx0 + (ch0 ^ sx0)];
        u32x4 a01 = win[r0 + bx1 + (ch0 ^ sx1)];
        u32x4 a10 = win[r1 + bx0 + (ch0 ^ sx0)];
        u32x4 a11 = win[r1 + bx1 + (ch0 ^ sx1)];
        u32x4 b00 = win[r0 + bx0 + (ch1 ^ sx0)];
        u32x4 b01 = win[r0 + bx1 + (ch1 ^ sx1)];
        u32x4 b10 = win[r1 + bx0 + (ch1 ^ sx0)];
        u32x4 b11 = win[r1 + bx1 + (ch1 ^ sx1)];

        // (5) rare out-of-window fallback (global reload under exec mask)
        if (!in0) {
            a00 = *(const u32x4*)(nb + ((size_t)y0c * WW + x0c) * CC + ch0 * 8);
            a01 = *(const u32x4*)(nb + ((size_t)y0c * WW + x1c) * CC + ch0 * 8);
            b00 = *(const u32x4*)(nb + ((size_t)y0c * WW + x0c) * CC + ch1 * 8);
            b01 = *(const u32x4*)(nb + ((size_t)y0c * WW + x1c) * CC + ch1 * 8);
        }
        if (!in1) {
            a10 = *(const u32x4*)(nb + ((size_t)y1c * WW + x0c) * CC + ch0 * 8);
            a11 = *(const u32x4*)(nb + ((size_t)y1c * WW + x1c) * CC + ch0 * 8);
            b10 = *(const u32x4*)(nb + ((size_t)y1c * WW + x0c) * CC + ch1 * 8);
            b11 = *(const u32x4*)(nb + ((size_t)y1c * WW + x1c) * CC + ch1 * 8);
        }

        // (6) blend + pack + MFMA, ks = 0 then 1
        #pragma unroll
        for (int ks = 0; ks < 2; ++ks) {
            const u32x4 w00 = ks ? b00 : a00;
            const u32x4 w01 = ks ? b01 : a01;
            const u32x4 w10 = ks ? b10 : a10;
            const u32x4 w11 = ks ? b11 : a11;
            u32x4 pk;
            #pragma unroll
            for (int j = 0; j < 4; ++j) {
                const float a0 = __uint_as_float(w00[j] << 16);
                const float a1 = __uint_as_float(w00[j] & 0xFFFF0000u);
                const float b0 = __uint_as_float(w01[j] << 16);
                const float b1 = __uint_as_float(w01[j] & 0xFFFF0000u);
                const float d0 = __uint_as_float(w10[j] << 16);
                const float d1 = __uint_as_float(w10[j] & 0xFFFF0000u);
                const float e0 = __uint_as_float(w11[j] << 16);
                const float e1 = __uint_as_float(w11[j] & 0xFFFF0000u);
                const float s0f = c00 * a0 + c01 * b0 + c10 * d0 + c11 * e0;
                const float s1f = c00 * a1 + c01 * b1 + c10 * d1 + c11 * e1;
                pk[j] = f32_to_bf16_rne(s0f) | (f32_to_bf16_rne(s1f) << 16);
            }
            const bf16x8 bfrag = __builtin_bit_cast(bf16x8, pk);
            const bf16x8 af0 = __builtin_bit_cast(bf16x8, ks ? wb0 : wa0);
            const bf16x8 af1 = __builtin_bit_cast(bf16x8, ks ? wb1 : wa1);
            const bf16x8 af2 = __builtin_bit_cast(bf16x8, ks ? wb2 : wa2);
            const bf16x8 af3 = __builtin_bit_cast(bf16x8, ks ? wb3 : wa3);
            acc[0] = __builtin_amdgcn_mfma_f32_16x16x32_bf16(af0, bfrag, acc[0], 0, 0, 0);
            acc[1] = __builtin_amdgcn_mfma_f32_16x16x32_bf16(af1, bfrag, acc[1], 0, 0, 0);
            acc[2] = __builtin_amdgcn_mfma_f32_16x16x32_bf16(af2, bfrag, acc[2], 0, 0, 0);
            acc[3] = __builtin_amdgcn_mfma_f32_16x16x32_bf16(af3, bfrag, acc[3], 0, 0, 0);
        }

        // (7) incremental kt/3, kt%3
        if (++kx == 3) { kx = 0; ++ky; }
    }

    // ---- epilogue: C/D layout col=lane&15 (pixel), row=kq*4+reg (o) ----
    #pragma unroll
    for (int mt = 0; mt < 4; ++mt) {
        const f32x4 bv = *(const f32x4*)(bias + mt * 16 + kq * 4);
        #pragma unroll
        for (int r = 0; r < 4; ++r) {
            const int o = mt * 16 + kq * 4 + r;
            out[((b * 64 + o) * 128 + h) * 128 + wpix] = acc[mt][r] + bv[r];
        }
    }
}

extern "C" void kernel_launch(void* const* d_in, const int* in_sizes, int n_in,
                              void* d_out, int out_size, void* d_ws, size_t ws_size,
                              hipStream_t stream)
{
    const float* input  = (const float*)d_in[0];
    // d_in[1] = depth, unused by the reference
    const float* offset = (const float*)d_in[2];
    const float* mask   = (const float*)d_in[3];
    const float* weight = (const float*)d_in[4];
    const float* bias   = (const float*)d_in[5];
    float* out = (float*)d_out;

    unsigned short* nhwc = (unsigned short*)d_ws;                    // 8.39 MB
    unsigned short* wT2  = nhwc + (size_t)4 * HW * CC;               // 73728 B

    prep_fused14<<<dim3(2066), dim3(256), 0, stream>>>(input, nhwc, weight, wT2);
    ddc_roll14<<<dim3(512), dim3(512), 0, stream>>>(nhwc, wT2, offset, mask, bias, out);
}

// Round 7
// 104.646 us; speedup vs baseline: 1.0540x; 1.0540x over previous
//
#include <hip/hip_runtime.h>

// DepthDeformConv — round 15: r12 shape, register pressure removed.
//   r12 (1024thr, 4 waves/SIMD) gave the best TOTAL but its VGPR collapsed
//   to 56 (128 cap, 27-scalar prefetch + buffers) -> ILP destroyed, main
//   50.5us. r11/r13 had ILP but only 2 waves/SIMD. Never tested: 4 waves
//   per SIMD WITH intact ILP. This round: 1024thr / 16 waves / 8-row
//   128KB window / 1 barrier / 256 blocks, body slimmed to fit ~100 VGPR:
//   offset/mask staged to LDS (27KB, broadcast reads, no prefetch arrays),
//   per-ks weight+corner chunks (32 live VGPR not 64), blend as f32x2
//   (v_pk_fma_f32) + v_cvt_pk_bf16_f32 pack (RNE, bit-identical) cutting
//   tap VALU ~40%. prep: float4 input loads.

typedef __attribute__((ext_vector_type(8))) short bf16x8;
typedef __attribute__((ext_vector_type(4))) float f32x4;
typedef __attribute__((ext_vector_type(2))) float f32x2;
typedef __attribute__((ext_vector_type(4))) unsigned int u32x4;

#define HH 128
#define WW 128
#define CC 64
#define OO 64
#define HW (128 * 128)

__device__ __forceinline__ unsigned f32_to_bf16_rne(float f) {
    unsigned u = __float_as_uint(f);
    return (u + 0x7FFFu + ((u >> 16) & 1u)) >> 16;
}

// ---------------- kernel 1: fused NCHW->NHWC bf16 + weight repack ----------------
__global__ __launch_bounds__(256)
void prep_fused15(const float* __restrict__ input,
                  unsigned short* __restrict__ nhwc,
                  const float* __restrict__ weight,
                  unsigned short* __restrict__ wT2)
{
    __shared__ unsigned tile[64][33];
    const int tid = threadIdx.x;
    const int blk = blockIdx.x;

    if (blk >= 2048) {
        // weight repack: wT2[(kt*8 + c8)*64 + o] = bf16 w for ch c8*8..+7, tap kt
        const int d  = (blk - 2048) * 256 + tid;    // 0..4607
        const int o  = d & 63;
        const int k8 = d >> 6;                      // 0..71
        const int kt = k8 >> 3;
        const int c8 = k8 & 7;
        u32x4 pk;
        #pragma unroll
        for (int jj = 0; jj < 4; ++jj) {
            unsigned lo = f32_to_bf16_rne(weight[o * 576 + (c8 * 8 + 2 * jj)     * 9 + kt]);
            unsigned hi = f32_to_bf16_rne(weight[o * 576 + (c8 * 8 + 2 * jj + 1) * 9 + kt]);
            pk[jj] = lo | (hi << 16);
        }
        *(u32x4*)(wT2 + (size_t)d * 8) = pk;
        return;
    }

    const int b  = blk >> 9;
    const int y  = (blk >> 2) & 127;
    const int xbase = (blk & 3) * 32;
    #pragma unroll
    for (int it = 0; it < 2; ++it) {
        int flat = it * 256 + tid;          // 0..511
        int c = flat >> 3, x4 = flat & 7;   // 64c x 8 float4-groups
        const f32x4 v = *(const f32x4*)(input + ((b * 64 + c) * 128 + y) * 128 + xbase + x4 * 4);
        tile[c][x4 * 4 + 0] = f32_to_bf16_rne(v[0]);
        tile[c][x4 * 4 + 1] = f32_to_bf16_rne(v[1]);
        tile[c][x4 * 4 + 2] = f32_to_bf16_rne(v[2]);
        tile[c][x4 * 4 + 3] = f32_to_bf16_rne(v[3]);
    }
    __syncthreads();
    {
        int x = tid >> 3, cg = tid & 7;     // 32x * 8 channel-groups
        unsigned r0 = tile[cg * 8 + 0][x], r1 = tile[cg * 8 + 1][x];
        unsigned r2 = tile[cg * 8 + 2][x], r3 = tile[cg * 8 + 3][x];
        unsigned r4 = tile[cg * 8 + 4][x], r5 = tile[cg * 8 + 5][x];
        unsigned r6 = tile[cg * 8 + 6][x], r7 = tile[cg * 8 + 7][x];
        u32x4 pk;
        pk[0] = r0 | (r1 << 16); pk[1] = r2 | (r3 << 16);
        pk[2] = r4 | (r5 << 16); pk[3] = r6 | (r7 << 16);
        *(u32x4*)(nhwc + ((size_t)((b * 128 + y) * 128 + xbase + x)) * 64 + cg * 8) = pk;
    }
}

// ---------------- kernel 2: fused sample + MFMA, 16-wave slim body ----------------
__global__ __launch_bounds__(1024)
void ddc_slim15(const unsigned short* __restrict__ nhwc,
                const unsigned short* __restrict__ wT2,
                const float* __restrict__ offset,
                const float* __restrict__ mask,
                const float* __restrict__ bias,
                float* __restrict__ out)
{
    // 8-row bf16 NHWC window, chunk-swizzled: LDS u32x4 index
    //   idx(slot,x,c8pos) = slot*1024 + x*8 + c8pos, holding source chunk
    //   c8pos ^ (x&7). Reader at chunk ch uses pos = ch ^ (x&7).
    __shared__ u32x4 win[8192];            // 128 KB
    __shared__ float sten[6912];           // 27 KB: [plane 0..26][hr 0..1][x 0..127]

    const int blk0 = blockIdx.x;           // 256 = 4b * 64 h-pairs
    const int blk  = (blk0 & 7) * 32 + (blk0 >> 3);   // XCD-chunked swizzle
    const int b    = blk >> 6;
    const int h0   = (blk & 63) * 2;
    const int ys   = h0 - 3;               // window start row
    const int tid  = threadIdx.x;
    const int wave = tid >> 6;             // 16 waves
    const int lane = tid & 63;
    const int l15  = lane & 15;            // pixel within group / o-row (A)
    const int kq   = lane >> 4;            // k-chunk quad (0..3)
    const int hr   = wave >> 3;            // waves 0-7 -> h0, 8-15 -> h0+1
    const int h    = h0 + hr;
    const int wpix = (wave & 7) * 16 + l15;

    f32x4 acc[4];
    #pragma unroll
    for (int mt = 0; mt < 4; ++mt) acc[mt] = (f32x4){0.f, 0.f, 0.f, 0.f};

    const unsigned short* nb = nhwc + (size_t)b * HW * CC;
    const u32x4* wsrc = (const u32x4*)wT2;

    // ---- stage offset/mask planes for both rows (27 planes x 2 x 128) ----
    #pragma unroll
    for (int it = 0; it < 7; ++it) {
        const int f = it * 1024 + tid;                // 0..7167
        if (f < 6912) {
            const int plane = f >> 8;                 // 0..26
            const int fr    = (f >> 7) & 1;
            const int x     = f & 127;
            sten[f] = (plane < 18)
                ? offset[((b * 18 + plane)      * 128 + (h0 + fr)) * 128 + x]
                : mask  [((b * 9 + (plane - 18))* 128 + (h0 + fr)) * 128 + x];
        }
    }

    // ---- stage window rows ys..ys+7 (swizzled source, linear LDS dest) ----
    #pragma unroll
    for (int slot = 0; slot < 8; ++slot) {
        const int y = ys + slot;
        if (y >= 0 && y < HH) {
            const int q  = tid;                       // 0..1023 = one full row
            const int x  = q >> 3;
            const int c8 = q & 7;
            win[slot * 1024 + q] =
                *(const u32x4*)(nb + ((size_t)(y * WW + x)) * CC + ((c8 ^ (x & 7)) << 3));
        }
    }
    __syncthreads();                                  // the ONLY barrier

    // ---- K loop: fully unrolled, barrier-free, slim per-ks chunks ----
    #pragma unroll
    for (int kt = 0; kt < 9; ++kt) {
        // stencil scalars from LDS (16-lane broadcast, conflict-free)
        const float oy = sten[(2 * kt)     * 256 + hr * 128 + wpix];
        const float ox = sten[(2 * kt + 1) * 256 + hr * 128 + wpix];
        const float m  = sten[(18 + kt)    * 256 + hr * 128 + wpix];

        const float py = (float)(h - 1 + kt / 3) + oy;
        const float px = (float)(wpix - 1 + kt % 3) + ox;
        const float y0f = floorf(py), x0f = floorf(px);
        const int y0 = (int)y0f, x0 = (int)x0f;
        const float wy = py - y0f, wx = px - x0f;
        const int y1 = y0 + 1, x1 = x0 + 1;
        const bool vy0 = (y0 >= 0) & (y0 < HH);
        const bool vy1 = (y1 >= 0) & (y1 < HH);
        const bool vx0 = (x0 >= 0) & (x0 < WW);
        const bool vx1 = (x1 >= 0) & (x1 < WW);
        const int y0c = min(max(y0, 0), HH - 1), y1c = min(max(y1, 0), HH - 1);
        const int x0c = min(max(x0, 0), WW - 1), x1c = min(max(x1, 0), WW - 1);
        const float wy1 = 1.f - wy, wx1 = 1.f - wx;
        const float c00 = (vy0 && vx0) ? wy1 * wx1 * m : 0.f;
        const float c01 = (vy0 && vx1) ? wy1 * wx  * m : 0.f;
        const float c10 = (vy1 && vx0) ? wy  * wx1 * m : 0.f;
        const float c11 = (vy1 && vx1) ? wy  * wx  * m : 0.f;

        const int s0 = y0c - ys, s1 = y1c - ys;
        const bool in0 = ((unsigned)s0 < 8u);
        const bool in1 = ((unsigned)s1 < 8u);
        const int r0 = (in0 ? s0 : 0) * 1024;
        const int r1 = (in1 ? s1 : 0) * 1024;
        const int bx0 = x0c * 8, sx0 = x0c & 7;
        const int bx1 = x1c * 8, sx1 = x1c & 7;

        const f32x2 vc00 = (f32x2){c00, c00}, vc01 = (f32x2){c01, c01};
        const f32x2 vc10 = (f32x2){c10, c10}, vc11 = (f32x2){c11, c11};

        #pragma unroll
        for (int ks = 0; ks < 2; ++ks) {
            const int ch = ks * 4 + kq;       // this lane's 8-channel chunk

            u32x4 w00 = win[r0 + bx0 + (ch ^ sx0)];
            u32x4 w01 = win[r0 + bx1 + (ch ^ sx1)];
            u32x4 w10 = win[r1 + bx0 + (ch ^ sx0)];
            u32x4 w11 = win[r1 + bx1 + (ch ^ sx1)];
            if (!in0) {                       // rare: |oy| past window
                w00 = *(const u32x4*)(nb + ((size_t)y0c * WW + x0c) * CC + ch * 8);
                w01 = *(const u32x4*)(nb + ((size_t)y0c * WW + x1c) * CC + ch * 8);
            }
            if (!in1) {
                w10 = *(const u32x4*)(nb + ((size_t)y1c * WW + x0c) * CC + ch * 8);
                w11 = *(const u32x4*)(nb + ((size_t)y1c * WW + x1c) * CC + ch * 8);
            }

            u32x4 pk;
            #pragma unroll
            for (int j = 0; j < 4; ++j) {
                const f32x2 A = (f32x2){__uint_as_float(w00[j] << 16),
                                        __uint_as_float(w00[j] & 0xFFFF0000u)};
                const f32x2 B = (f32x2){__uint_as_float(w01[j] << 16),
                                        __uint_as_float(w01[j] & 0xFFFF0000u)};
                const f32x2 D = (f32x2){__uint_as_float(w10[j] << 16),
                                        __uint_as_float(w10[j] & 0xFFFF0000u)};
                const f32x2 E = (f32x2){__uint_as_float(w11[j] << 16),
                                        __uint_as_float(w11[j] & 0xFFFF0000u)};
                const f32x2 S = vc00 * A + vc01 * B + vc10 * D + vc11 * E;
                unsigned r;
                asm("v_cvt_pk_bf16_f32 %0, %1, %2" : "=v"(r) : "v"(S[0]), "v"(S[1]));
                pk[j] = r;
            }
            const bf16x8 bfrag = __builtin_bit_cast(bf16x8, pk);

            // A-fragments from global (wT2 72KB, L2-resident)
            const u32x4* wp = wsrc + (kt * 8 + ks * 4 + kq) * 64 + l15;
            acc[0] = __builtin_amdgcn_mfma_f32_16x16x32_bf16(
                __builtin_bit_cast(bf16x8, wp[0]),  bfrag, acc[0], 0, 0, 0);
            acc[1] = __builtin_amdgcn_mfma_f32_16x16x32_bf16(
                __builtin_bit_cast(bf16x8, wp[16]), bfrag, acc[1], 0, 0, 0);
            acc[2] = __builtin_amdgcn_mfma_f32_16x16x32_bf16(
                __builtin_bit_cast(bf16x8, wp[32]), bfrag, acc[2], 0, 0, 0);
            acc[3] = __builtin_amdgcn_mfma_f32_16x16x32_bf16(
                __builtin_bit_cast(bf16x8, wp[48]), bfrag, acc[3], 0, 0, 0);
        }
    }

    // ---- epilogue: C/D layout col=lane&15 (pixel), row=kq*4+reg (o) ----
    #pragma unroll
    for (int mt = 0; mt < 4; ++mt) {
        const f32x4 bv = *(const f32x4*)(bias + mt * 16 + kq * 4);
        #pragma unroll
        for (int r = 0; r < 4; ++r) {
            const int o = mt * 16 + kq * 4 + r;
            out[((b * 64 + o) * 128 + h) * 128 + wpix] = acc[mt][r] + bv[r];
        }
    }
}

extern "C" void kernel_launch(void* const* d_in, const int* in_sizes, int n_in,
                              void* d_out, int out_size, void* d_ws, size_t ws_size,
                              hipStream_t stream)
{
    const float* input  = (const float*)d_in[0];
    // d_in[1] = depth, unused by the reference
    const float* offset = (const float*)d_in[2];
    const float* mask   = (const float*)d_in[3];
    const float* weight = (const float*)d_in[4];
    const float* bias   = (const float*)d_in[5];
    float* out = (float*)d_out;

    unsigned short* nhwc = (unsigned short*)d_ws;                    // 8.39 MB
    unsigned short* wT2  = nhwc + (size_t)4 * HW * CC;               // 73728 B

    prep_fused15<<<dim3(2066), dim3(256), 0, stream>>>(input, nhwc, weight, wT2);
    ddc_slim15<<<dim3(256), dim3(1024), 0, stream>>>(nhwc, wT2, offset, mask, bias, out);
}